// Round 1
// baseline (264.399 us; speedup 1.0000x reference)
//
#include <hip/hip_runtime.h>
#include <math.h>

// Problem: B=32, S=2048, H=1024
//   d_out (float): [0] loss | [1..131073) logits (32,2048,2) | [131073..196609) header_mask
//
// R10: port sr_gemm9's K-loop from 2-phase (1 barrier/K-tile, vmcnt-drain) to the
// 8-phase counted-vmcnt schedule (T3+T4) + setprio(T5). Half-tile (128x64) staging
// into a 4-slot ring per matrix, vmcnt(6) once per K-tile (3 halves in flight),
// never drained in steady state. Data layout / swizzle / accumulation order are
// byte-identical to R9, so results are bit-identical. Tail stages clamp to kt=15
// into dead slots (never read) to keep the loop guard-free; one vmcnt(0)+barrier
// after the loop fences the red[] LDS reuse.

typedef __bf16 bf16x8 __attribute__((ext_vector_type(8)));
typedef float f32x4 __attribute__((ext_vector_type(4)));

struct alignas(16) BF8 { __bf16 h[8]; };
struct alignas(8)  BF4 { __bf16 h[4]; };

typedef const __attribute__((address_space(1))) void glb_void;
typedef __attribute__((address_space(3))) void lds_void;

#define SEQ 2048
#define NB  32
#define HID 1024
#define MROWS (NB * SEQ)          // 65536
#define NKT 16                    // K tiles of 64

// branch-free exact-GELU via A&S 7.1.26 erf approximation (|eps| < 1.5e-7)
__device__ __forceinline__ float gelu_bf(float x) {
    float z  = 0.70710678118f * x;
    float az = fabsf(z);
    float t  = __builtin_amdgcn_rcpf(fmaf(0.3275911f, az, 1.0f));
    float poly = fmaf(fmaf(fmaf(fmaf(1.061405429f, t, -1.453152027f), t,
                         1.421413741f), t, -0.284496736f), t, 0.254829592f) * t;
    float ex = __expf(-az * az);
    float er = copysignf(fmaf(-poly, ex, 1.0f), z);
    return 0.5f * x * (1.0f + er);
}

// ---------------- init logits with b2 (FALLBACK path only) ----------------------
__global__ void sr_init_logits(float* __restrict__ logits, const float* __restrict__ b2) {
    int i = blockIdx.x * 256 + threadIdx.x;
    if (i < MROWS * 2) logits[i] = b2[i & 1];
}

// ---------------- W1 first half -> bf16 -----------------------------------------
__global__ void sr_conv_w1(const float* __restrict__ W1, __bf16* __restrict__ Bt) {
    int gid = blockIdx.x * 256 + threadIdx.x;
    int h = gid >> 8;
    int kb = (gid & 255) * 4;
    float4 v = *(const float4*)&W1[(size_t)h * 2048 + kb];
    BF4 o;
    o.h[0] = (__bf16)v.x; o.h[1] = (__bf16)v.y; o.h[2] = (__bf16)v.z; o.h[3] = (__bf16)v.w;
    *(BF4*)&Bt[(size_t)h * 1024 + kb] = o;
}

// ---------------- enc f32 -> bf16 (Ab) ------------------------------------------
__global__ void sr_conv_enc(const float* __restrict__ enc, __bf16* __restrict__ Ab) {
    size_t i = ((size_t)blockIdx.x * 256 + threadIdx.x) * 8;
    float4 v0 = *(const float4*)&enc[i];
    float4 v1 = *(const float4*)&enc[i + 4];
    BF8 t;
    t.h[0] = (__bf16)v0.x; t.h[1] = (__bf16)v0.y;
    t.h[2] = (__bf16)v0.z; t.h[3] = (__bf16)v0.w;
    t.h[4] = (__bf16)v1.x; t.h[5] = (__bf16)v1.y;
    t.h[6] = (__bf16)v1.z; t.h[7] = (__bf16)v1.w;
    *(BF8*)&Ab[i] = t;
}

// ---------------- formula embedding: index-gather (labels scanned, not enc) -----
__global__ void sr_femb(const float* __restrict__ enc, const int* __restrict__ lab,
                        float* __restrict__ femb) {
    __shared__ int cnt;
    __shared__ int idl[64];                 // plenty: exactly 1 hit/sample by construction
    int b = blockIdx.x;
    int tid = threadIdx.x;
    if (tid == 0) cnt = 0;
    __syncthreads();
    for (int s = tid; s < SEQ; s += 256)
        if (lab[b * SEQ + s] == 2) {
            int p = atomicAdd(&cnt, 1);
            if (p < 64) idl[p] = s;
        }
    __syncthreads();
    float4 a = {0.f, 0.f, 0.f, 0.f};
    int n = cnt < 64 ? cnt : 64;
    for (int i = 0; i < n; ++i) {
        float4 v = *(const float4*)&enc[((size_t)b * SEQ + idl[i]) * HID + tid * 4];
        a.x += v.x; a.y += v.y; a.z += v.z; a.w += v.w;
    }
    *(float4*)&femb[b * HID + tid * 4] = a;
}

// ---------------- fc[b,h] = b1[h] + femb[b,:] . W1[h,1024:2048] -----------------
__global__ void sr_fc(const float* __restrict__ femb, const float* __restrict__ W1,
                      const float* __restrict__ b1, float* __restrict__ fcout) {
    int gw = (blockIdx.x * 256 + threadIdx.x) >> 6;
    int lane = threadIdx.x & 63;
    for (int i = 0; i < 16; ++i) {
        int d = gw * 16 + i;
        int b = d >> 10, h = d & 1023;
        const float* fe = femb + b * HID;
        const float* wr = W1 + (size_t)h * 2048 + 1024;
        float p = 0.f;
        #pragma unroll
        for (int t = 0; t < 16; ++t) {
            int k = lane + t * 64;
            p += fe[k] * wr[k];
        }
        #pragma unroll
        for (int off = 32; off; off >>= 1) p += __shfl_down(p, off);
        if (lane == 0) fcout[d] = p + b1[h];
    }
}

// ---------------- PRIMARY: 256^2 8-phase GEMM + LDS-transpose epilogue ----------
__global__ __launch_bounds__(512, 2)
void sr_gemm9(const __bf16* __restrict__ Ab, const __bf16* __restrict__ Bt,
              const float* __restrict__ fc, const float* __restrict__ W2,
              float* __restrict__ partg) {
    // 139264 B: loop uses first 131072 as 4 half-slots per matrix (16 KB each);
    // epilogue reuses all as red[]
    __shared__ __align__(16) unsigned char smem[139264];
    __bf16* LAb = (__bf16*)smem;                    // A slots: LAb + slot*8192
    __bf16* LBb = (__bf16*)(smem + 65536);          // B slots: LBb + slot*8192
    float*  red = (float*)smem;                     // [256*2][68] f32 epilogue scratch

    int bid = blockIdx.x;
    int lgc = (bid & 7) * 128 + (bid >> 3);         // XCD-bijective (1024 % 8 == 0)
    int pm = lgc >> 2, pn = lgc & 3;
    const int row0 = pm * 256, col0 = pn * 256;

    int tid = threadIdx.x;
    int wid = tid >> 6, lane = tid & 63;
    int wr = wid >> 2, wc = wid & 3;
    int l15 = lane & 15, lq = lane >> 4;

    f32x4 acc[2][2][4][2] = {};
    bf16x8 af[4][2];            // current-qa A frags (live 2 phases)
    bf16x8 bfr[2][2][2];        // both B halves' frags (h0 live P1->P3, h1 P2->P4)

    // stage one 128x64 half-tile (2 x global_load_lds dwordx4 per thread)
    #define STG(SRC, ROWB, LBASE, SLOT, KT, HH) do {                              \
        _Pragma("unroll")                                                         \
        for (int i = 0; i < 2; ++i) {                                             \
            int q = i * 512 + tid;                                                \
            int r = q >> 3, c = q & 7;                                            \
            int sc = (c ^ (r & 7)) * 8 + (KT) * 64;                               \
            __builtin_amdgcn_global_load_lds(                                     \
                (glb_void*)((SRC) + (size_t)((ROWB) + (HH) * 128 + r) * HID + sc),\
                (lds_void*)((LBASE) + (SLOT) * 8192 + q * 8), 16, 0, 0);          \
        }                                                                         \
    } while (0)

    #define RD_A(HB)                                                              \
        _Pragma("unroll") for (int m = 0; m < 4; ++m)                             \
        _Pragma("unroll") for (int kk = 0; kk < 2; ++kk) {                        \
            int r = wr * 64 + m * 16 + l15;                                       \
            af[m][kk] = *(const bf16x8*)&(HB)[r * 64 + (((kk*4+lq) ^ (r&7)) * 8)];\
        }

    #define RD_B(QB, HB)                                                          \
        _Pragma("unroll") for (int n = 0; n < 2; ++n)                             \
        _Pragma("unroll") for (int kk = 0; kk < 2; ++kk) {                        \
            int r = wc * 32 + n * 16 + l15;                                       \
            bfr[QB][n][kk] = *(const bf16x8*)&(HB)[r * 64 + (((kk*4+lq) ^ (r&7)) * 8)];\
        }

    #define MM(QA, QB)                                                            \
        _Pragma("unroll") for (int m = 0; m < 4; ++m)                             \
        _Pragma("unroll") for (int n = 0; n < 2; ++n)                             \
        _Pragma("unroll") for (int kk = 0; kk < 2; ++kk)                          \
            acc[QA][QB][m][n] = __builtin_amdgcn_mfma_f32_16x16x32_bf16(          \
                af[m][kk], bfr[QB][n][kk], acc[QA][QB][m][n], 0, 0, 0);

    #define BAR()  __builtin_amdgcn_s_barrier()
    #define LGKM0() do { asm volatile("s_waitcnt lgkmcnt(0)" ::: "memory");       \
                         __builtin_amdgcn_sched_barrier(0); } while (0)

    // One K-tile = 4 phases. SA: this tile's half-slot base (0 or 2), halves at
    // SA/SA+1 for both A and B. SNB: slot of B(kt+1,h0). K1=kt+1, K2=kt+2
    // (clamped to 15 at the tail -> stages land in dead slots, never read).
    #define KTILE(SA, SNB, K1, K2)                                                \
    {                                                                             \
        const __bf16* LA0 = LAb + (SA) * 8192;                                    \
        const __bf16* LA1 = LA0 + 8192;                                           \
        const __bf16* LB0 = LBb + (SA) * 8192;                                    \
        const __bf16* LB1 = LB0 + 8192;                                           \
        /* P1: A-h0 + B-h0 frags; stage B(kt+1,h0); mfma (qa0,qb0) */             \
        RD_A(LA0);                                                                \
        RD_B(0, LB0);                                                             \
        STG(Bt, col0, LBb, SNB, K1, 0);                                           \
        BAR(); LGKM0();                                                           \
        __builtin_amdgcn_s_setprio(1);                                            \
        MM(0, 0);                                                                 \
        __builtin_amdgcn_s_setprio(0);                                            \
        BAR();                                                                    \
        /* P2: B-h1 frags; stage A(kt+2,h0); mfma (qa0,qb1) */                    \
        RD_B(1, LB1);                                                             \
        STG(Ab, row0, LAb, SA, K2, 0);                                            \
        BAR(); LGKM0();                                                           \
        __builtin_amdgcn_s_setprio(1);                                            \
        MM(0, 1);                                                                 \
        __builtin_amdgcn_s_setprio(0);                                            \
        BAR();                                                                    \
        /* P3: A-h1 frags; stage B(kt+2,h1); mfma (qa1,qb0) reusing bfr[0] */     \
        RD_A(LA1);                                                                \
        STG(Bt, col0, LBb, (SA) + 1, K2, 1);                                      \
        BAR(); LGKM0();                                                           \
        __builtin_amdgcn_s_setprio(1);                                            \
        MM(1, 0);                                                                 \
        __builtin_amdgcn_s_setprio(0);                                            \
        BAR();                                                                    \
        /* P4: stage A(kt+2,h1); mfma (qa1,qb1); counted vmcnt (never 0) */       \
        STG(Ab, row0, LAb, (SA) + 1, K2, 1);                                      \
        BAR();                                                                    \
        __builtin_amdgcn_s_setprio(1);                                            \
        MM(1, 1);                                                                 \
        __builtin_amdgcn_s_setprio(0);                                            \
        asm volatile("s_waitcnt vmcnt(6)" ::: "memory");                          \
        __builtin_amdgcn_sched_barrier(0);                                        \
        BAR();                                                                    \
    }

    // prologue: 7 halves in flight, first 4 (= kt0's needs) forced complete
    STG(Ab, row0, LAb, 0, 0, 0);        // A(0,0)
    STG(Bt, col0, LBb, 0, 0, 0);        // B(0,0)
    STG(Bt, col0, LBb, 1, 0, 1);        // B(0,1)
    STG(Ab, row0, LAb, 1, 0, 1);        // A(0,1)
    STG(Ab, row0, LAb, 2, 1, 0);        // A(1,0)
    STG(Bt, col0, LBb, 3, 1, 1);        // B(1,1)
    STG(Ab, row0, LAb, 3, 1, 1);        // A(1,1)
    asm volatile("s_waitcnt vmcnt(6)" ::: "memory");
    __builtin_amdgcn_sched_barrier(0);
    BAR();

    for (int u = 0; u < 8; ++u) {
        int kt0 = 2 * u, kt1 = 2 * u + 1;
        int k2a = (kt0 + 2 < NKT) ? kt0 + 2 : NKT - 1;
        int k2b = (kt1 + 2 < NKT) ? kt1 + 2 : NKT - 1;
        KTILE(0, 2, kt1, k2a);          // even K-tile: halves in slots 0/1
        KTILE(2, 0, k2a, k2b);          // odd  K-tile: halves in slots 2/3
    }

    // drain the clamped tail stages before red[] aliases the slot rings
    asm volatile("s_waitcnt vmcnt(0)" ::: "memory");
    __builtin_amdgcn_sched_barrier(0);
    BAR();

    #undef KTILE
    #undef STG
    #undef RD_A
    #undef RD_B
    #undef MM
    #undef BAR
    #undef LGKM0

    // ---- epilogue: per-lane gelu+W2 partials -> LDS transpose -> tree-free sum --
    int b = row0 >> 11;
    float fcv[2][2], w2a[2][2], w2b[2][2];
    #pragma unroll
    for (int qb = 0; qb < 2; ++qb)
        #pragma unroll
        for (int n = 0; n < 2; ++n) {
            int h = col0 + qb * 128 + wc * 32 + n * 16 + l15;
            fcv[qb][n] = fc[b * HID + h];
            w2a[qb][n] = W2[h];
            w2b[qb][n] = W2[HID + h];
        }
    int e = wc * 16 + l15;                  // 0..63: which h-subgroup this lane covers
    #pragma unroll
    for (int qa = 0; qa < 2; ++qa)
        #pragma unroll
        for (int m = 0; m < 4; ++m)
            #pragma unroll
            for (int j = 0; j < 4; ++j) {
                int rloc = qa * 128 + wr * 64 + m * 16 + lq * 4 + j;
                float p0 = 0.f, p1 = 0.f;
                #pragma unroll
                for (int qb = 0; qb < 2; ++qb)
                    #pragma unroll
                    for (int n = 0; n < 2; ++n) {
                        float g = gelu_bf(acc[qa][qb][m][n][j] + fcv[qb][n]);
                        p0 += g * w2a[qb][n];
                        p1 += g * w2b[qb][n];
                    }
                red[(rloc * 2 + 0) * 68 + e] = p0;
                red[(rloc * 2 + 1) * 68 + e] = p1;
            }
    __syncthreads();
    {   // one (row, class) per thread: sum 64 partials via 16 aligned b128 reads
        const f32x4* rp = (const f32x4*)&red[tid * 68];
        f32x4 sv = {0.f, 0.f, 0.f, 0.f};
        #pragma unroll
        for (int i = 0; i < 16; ++i) sv += rp[i];
        float s = sv[0] + sv[1] + sv[2] + sv[3];
        int row = tid >> 1, c = tid & 1;
        partg[((size_t)pn * MROWS + row0 + row) * 2 + c] = s;
    }
}

// ---------------- FALLBACK GEMM (atomics path, used only if ws too small) -------
__global__ __launch_bounds__(256, 2)
void sr_gemm_fused(const float* __restrict__ enc, const __bf16* __restrict__ Bt,
                   const float* __restrict__ fc, const float* __restrict__ W2,
                   float* __restrict__ logits) {
    __shared__ __bf16 As[128 * 64];
    __shared__ __bf16 Bs[128 * 64];

    int bid = blockIdx.x;
    int logical = (bid & 7) * 512 + (bid >> 3);
    int pm = logical >> 3;
    int pn = logical & 7;

    int tid = threadIdx.x;
    int wid = tid >> 6, lane = tid & 63;
    int wm = wid >> 1, wn = wid & 1;

    const int row0 = pm * 128;
    const int col0 = pn * 128;

    f32x4 acc[4][4] = {};

    for (int kt = 0; kt < 16; ++kt) {
        int k0 = kt * 64;
        #pragma unroll
        for (int i = 0; i < 4; ++i) {
            int q = i * 256 + tid;
            int r = q >> 3;
            int cb = (q & 7) * 8;
            const __bf16* src = Bt + (size_t)(col0 + r) * 1024 + k0 + cb;
            __builtin_amdgcn_global_load_lds((glb_void*)src, (lds_void*)&Bs[q * 8], 16, 0, 0);
        }
        #pragma unroll
        for (int pp = 0; pp < 4; ++pp) {
            int e = pp * 2048 + tid * 8;
            int r = e >> 6, c = e & 63;
            const float* src = enc + (size_t)(row0 + r) * 1024 + k0 + c;
            float4 f0 = *(const float4*)src;
            float4 f1 = *(const float4*)(src + 4);
            BF8 t;
            t.h[0] = (__bf16)f0.x; t.h[1] = (__bf16)f0.y;
            t.h[2] = (__bf16)f0.z; t.h[3] = (__bf16)f0.w;
            t.h[4] = (__bf16)f1.x; t.h[5] = (__bf16)f1.y;
            t.h[6] = (__bf16)f1.z; t.h[7] = (__bf16)f1.w;
            *(BF8*)&As[r * 64 + c] = t;
        }
        __syncthreads();
        int lrow = lane & 15;
        int ak = (lane >> 4) * 8;
        #pragma unroll
        for (int kk = 0; kk < 2; ++kk) {
            bf16x8 a[4], b[4];
            #pragma unroll
            for (int m = 0; m < 4; ++m)
                a[m] = *(const bf16x8*)&As[(wm * 64 + m * 16 + lrow) * 64 + kk * 32 + ak];
            #pragma unroll
            for (int n = 0; n < 4; ++n)
                b[n] = *(const bf16x8*)&Bs[(wn * 64 + n * 16 + lrow) * 64 + kk * 32 + ak];
            #pragma unroll
            for (int m = 0; m < 4; ++m)
                #pragma unroll
                for (int n = 0; n < 4; ++n)
                    acc[m][n] = __builtin_amdgcn_mfma_f32_16x16x32_bf16(a[m], b[n], acc[m][n], 0, 0, 0);
        }
        __syncthreads();
    }

    int bidx = row0 >> 11;
    float fcv[4], w2a[4], w2b[4];
    #pragma unroll
    for (int n = 0; n < 4; ++n) {
        int h = col0 + wn * 64 + n * 16 + (lane & 15);
        fcv[n] = fc[bidx * HID + h];
        w2a[n] = W2[h];
        w2b[n] = W2[HID + h];
    }
    #pragma unroll
    for (int m = 0; m < 4; ++m) {
        int rbase = row0 + wm * 64 + m * 16 + (lane >> 4) * 4;
        #pragma unroll
        for (int j = 0; j < 4; ++j) {
            float p0 = 0.f, p1 = 0.f;
            #pragma unroll
            for (int n = 0; n < 4; ++n) {
                float g = gelu_bf(acc[m][n][j] + fcv[n]);
                p0 += g * w2a[n];
                p1 += g * w2b[n];
            }
            #pragma unroll
            for (int off = 1; off < 16; off <<= 1) {
                p0 += __shfl_xor(p0, off);
                p1 += __shfl_xor(p1, off);
            }
            if ((lane & 15) == 0) {
                int rg = rbase + j;
                atomicAdd(&logits[rg * 2 + 0], p0);
                atomicAdd(&logits[rg * 2 + 1], p1);
            }
        }
    }
}

// ---------------- loss from partials: logits = b2 + sum_pn partg; CE ------------
__global__ void sr_loss_pg(const int* __restrict__ lab, const float* __restrict__ partg,
                           const float* __restrict__ b2, float* __restrict__ logits,
                           float* __restrict__ mask_out, float* __restrict__ sl,
                           float* __restrict__ validv) {
    int b = blockIdx.x;
    int tid = threadIdx.x;
    float b20 = b2[0], b21 = b2[1];
    float lsum = 0.f; int lcnt = 0;
    for (int s = tid; s < SEQ; s += 256) {
        size_t row = (size_t)b * SEQ + s;
        float l0 = b20, l1 = b21;
        #pragma unroll
        for (int q = 0; q < 4; ++q) {
            l0 += partg[((size_t)q * MROWS + row) * 2 + 0];
            l1 += partg[((size_t)q * MROWS + row) * 2 + 1];
        }
        logits[row * 2 + 0] = l0;
        logits[row * 2 + 1] = l1;
        int l = lab[row];
        bool hdr = (l == 0) || (l == 1);
        mask_out[row] = hdr ? 1.0f : 0.0f;
        if (hdr) {
            float mx = fmaxf(l0, l1);
            float lse = mx + logf(expf(l0 - mx) + expf(l1 - mx));
            lsum += lse - (l == 0 ? l0 : l1);
            lcnt++;
        }
    }
    #pragma unroll
    for (int off = 32; off; off >>= 1) {
        lsum += __shfl_down(lsum, off);
        lcnt += __shfl_down(lcnt, off);
    }
    __shared__ float wsum[4];
    __shared__ int wcnt[4];
    int wid = tid >> 6, lane = tid & 63;
    if (lane == 0) { wsum[wid] = lsum; wcnt[wid] = lcnt; }
    __syncthreads();
    if (tid == 0) {
        float S = wsum[0] + wsum[1] + wsum[2] + wsum[3];
        int C = wcnt[0] + wcnt[1] + wcnt[2] + wcnt[3];
        sl[b] = (C > 0) ? S / (float)C : 0.0f;
        validv[b] = (C > 0) ? 1.0f : 0.0f;
    }
}

// ---------------- loss reading logits directly (FALLBACK path) ------------------
__global__ void sr_loss(const int* __restrict__ lab, const float* __restrict__ logits,
                        float* __restrict__ mask_out, float* __restrict__ sl,
                        float* __restrict__ validv) {
    int b = blockIdx.x;
    int tid = threadIdx.x;
    float lsum = 0.f; int lcnt = 0;
    for (int s = tid; s < SEQ; s += 256) {
        int l = lab[b * SEQ + s];
        bool hdr = (l == 0) || (l == 1);
        mask_out[b * SEQ + s] = hdr ? 1.0f : 0.0f;
        if (hdr) {
            float l0 = logits[(b * SEQ + s) * 2];
            float l1 = logits[(b * SEQ + s) * 2 + 1];
            float mx = fmaxf(l0, l1);
            float lse = mx + logf(expf(l0 - mx) + expf(l1 - mx));
            lsum += lse - (l == 0 ? l0 : l1);
            lcnt++;
        }
    }
    #pragma unroll
    for (int off = 32; off; off >>= 1) {
        lsum += __shfl_down(lsum, off);
        lcnt += __shfl_down(lcnt, off);
    }
    __shared__ float wsum[4];
    __shared__ int wcnt[4];
    int wid = tid >> 6, lane = tid & 63;
    if (lane == 0) { wsum[wid] = lsum; wcnt[wid] = lcnt; }
    __syncthreads();
    if (tid == 0) {
        float S = wsum[0] + wsum[1] + wsum[2] + wsum[3];
        int C = wcnt[0] + wcnt[1] + wcnt[2] + wcnt[3];
        sl[b] = (C > 0) ? S / (float)C : 0.0f;
        validv[b] = (C > 0) ? 1.0f : 0.0f;
    }
}

__global__ void sr_final(const float* __restrict__ sl, const float* __restrict__ validv,
                         float* __restrict__ out) {
    if (threadIdx.x == 0) {
        float s = 0.f, v = 0.f;
        for (int b = 0; b < NB; ++b) { s += sl[b]; v += validv[b]; }
        out[0] = s / (v + 1e-6f);
    }
}

extern "C" void kernel_launch(void* const* d_in, const int* in_sizes, int n_in,
                              void* d_out, int out_size, void* d_ws, size_t ws_size,
                              hipStream_t stream) {
    const float* enc = (const float*)d_in[0];
    const int*   lab = (const int*)d_in[1];
    const float* W1  = (const float*)d_in[2];
    const float* b1  = (const float*)d_in[3];
    const float* W2  = (const float*)d_in[4];
    const float* b2  = (const float*)d_in[5];

    float* out     = (float*)d_out;
    float* loss    = out;
    float* logits  = out + 1;
    float* maskout = out + 1 + MROWS * 2;

    float* ws     = (float*)d_ws;
    float* femb   = ws;                            // 32768 f32
    float* fc     = ws + 32768;                    // 32768 f32
    float* sl     = ws + 65536;                    // 32
    float* validv = ws + 65568;                    // 32
    float* partg  = ws + 65600;                    // 524288 f32 (2 MB)
    __bf16* Bt    = (__bf16*)(ws + 65600 + 2 * 524288);  // 2 MB
    __bf16* Ab    = Bt + (size_t)HID * HID;              // 134.2 MB

    const size_t need = (65600u + 2u * 524288u) * 4u + (size_t)HID * HID * 2u
                      + (size_t)MROWS * HID * 2u;

    sr_conv_w1<<<1024, 256, 0, stream>>>(W1, Bt);
    sr_femb<<<32, 256, 0, stream>>>(enc, lab, femb);
    sr_fc<<<512, 256, 0, stream>>>(femb, W1, b1, fc);

    if (ws_size >= need) {
        sr_conv_enc<<<32768, 256, 0, stream>>>(enc, Ab);
        sr_gemm9<<<1024, 512, 0, stream>>>(Ab, Bt, fc, W2, partg);
        sr_loss_pg<<<32, 256, 0, stream>>>(lab, partg, b2, logits, maskout, sl, validv);
    } else {
        sr_init_logits<<<512, 256, 0, stream>>>(logits, b2);
        sr_gemm_fused<<<4096, 256, 0, stream>>>(enc, Bt, fc, W2, logits);
        sr_loss<<<32, 256, 0, stream>>>(lab, logits, maskout, sl, validv);
    }

    sr_final<<<1, 64, 0, stream>>>(sl, validv, loss);
}

// Round 2
// 263.234 us; speedup vs baseline: 1.0044x; 1.0044x over previous
//
#include <hip/hip_runtime.h>
#include <math.h>

// Problem: B=32, S=2048, H=1024
//   d_out (float): [0] loss | [1..131073) logits (32,2048,2) | [131073..196609) header_mask
//
// R11: revert R10's 8-phase schedule (regressed 164->184us: barrier density
// desynced pn-sibling blocks -> FETCH +22%, MfmaUtil -5pts). Back to R9's proven
// 2-phase loop, and instead DELETE sr_conv_enc (~60us: 268MB f32 read + 134MB
// bf16 write) by fusing the f32->bf16 A conversion into the GEMM staging:
// A is reg-staged (global f32 -> cvt -> ds_write_b128, T14 issue-early/write-late,
// compiler emits the counted vmcnt via data dependence), B stays global_load_lds
// from the small pre-converted Bt. Same (__bf16) cast -> bit-identical results.

typedef __bf16 bf16x8 __attribute__((ext_vector_type(8)));
typedef float f32x4 __attribute__((ext_vector_type(4)));

struct alignas(16) BF8 { __bf16 h[8]; };
struct alignas(8)  BF4 { __bf16 h[4]; };

typedef const __attribute__((address_space(1))) void glb_void;
typedef __attribute__((address_space(3))) void lds_void;

#define SEQ 2048
#define NB  32
#define HID 1024
#define MROWS (NB * SEQ)          // 65536
#define NKT 16                    // K tiles of 64

// branch-free exact-GELU via A&S 7.1.26 erf approximation (|eps| < 1.5e-7)
__device__ __forceinline__ float gelu_bf(float x) {
    float z  = 0.70710678118f * x;
    float az = fabsf(z);
    float t  = __builtin_amdgcn_rcpf(fmaf(0.3275911f, az, 1.0f));
    float poly = fmaf(fmaf(fmaf(fmaf(1.061405429f, t, -1.453152027f), t,
                         1.421413741f), t, -0.284496736f), t, 0.254829592f) * t;
    float ex = __expf(-az * az);
    float er = copysignf(fmaf(-poly, ex, 1.0f), z);
    return 0.5f * x * (1.0f + er);
}

// ---------------- init logits with b2 (FALLBACK path only) ----------------------
__global__ void sr_init_logits(float* __restrict__ logits, const float* __restrict__ b2) {
    int i = blockIdx.x * 256 + threadIdx.x;
    if (i < MROWS * 2) logits[i] = b2[i & 1];
}

// ---------------- W1 first half -> bf16 -----------------------------------------
__global__ void sr_conv_w1(const float* __restrict__ W1, __bf16* __restrict__ Bt) {
    int gid = blockIdx.x * 256 + threadIdx.x;
    int h = gid >> 8;
    int kb = (gid & 255) * 4;
    float4 v = *(const float4*)&W1[(size_t)h * 2048 + kb];
    BF4 o;
    o.h[0] = (__bf16)v.x; o.h[1] = (__bf16)v.y; o.h[2] = (__bf16)v.z; o.h[3] = (__bf16)v.w;
    *(BF4*)&Bt[(size_t)h * 1024 + kb] = o;
}

// ---------------- formula embedding: index-gather (labels scanned, not enc) -----
__global__ void sr_femb(const float* __restrict__ enc, const int* __restrict__ lab,
                        float* __restrict__ femb) {
    __shared__ int cnt;
    __shared__ int idl[64];                 // plenty: exactly 1 hit/sample by construction
    int b = blockIdx.x;
    int tid = threadIdx.x;
    if (tid == 0) cnt = 0;
    __syncthreads();
    for (int s = tid; s < SEQ; s += 256)
        if (lab[b * SEQ + s] == 2) {
            int p = atomicAdd(&cnt, 1);
            if (p < 64) idl[p] = s;
        }
    __syncthreads();
    float4 a = {0.f, 0.f, 0.f, 0.f};
    int n = cnt < 64 ? cnt : 64;
    for (int i = 0; i < n; ++i) {
        float4 v = *(const float4*)&enc[((size_t)b * SEQ + idl[i]) * HID + tid * 4];
        a.x += v.x; a.y += v.y; a.z += v.z; a.w += v.w;
    }
    *(float4*)&femb[b * HID + tid * 4] = a;
}

// ---------------- fc[b,h] = b1[h] + femb[b,:] . W1[h,1024:2048] -----------------
__global__ void sr_fc(const float* __restrict__ femb, const float* __restrict__ W1,
                      const float* __restrict__ b1, float* __restrict__ fcout) {
    int gw = (blockIdx.x * 256 + threadIdx.x) >> 6;
    int lane = threadIdx.x & 63;
    for (int i = 0; i < 16; ++i) {
        int d = gw * 16 + i;
        int b = d >> 10, h = d & 1023;
        const float* fe = femb + b * HID;
        const float* wr = W1 + (size_t)h * 2048 + 1024;
        float p = 0.f;
        #pragma unroll
        for (int t = 0; t < 16; ++t) {
            int k = lane + t * 64;
            p += fe[k] * wr[k];
        }
        #pragma unroll
        for (int off = 32; off; off >>= 1) p += __shfl_down(p, off);
        if (lane == 0) fcout[d] = p + b1[h];
    }
}

// ---------------- PRIMARY: 256^2 2-phase GEMM, A converted in-loop --------------
__global__ __launch_bounds__(512, 2)
void sr_gemm11(const float* __restrict__ enc, const __bf16* __restrict__ Bt,
               const float* __restrict__ fc, const float* __restrict__ W2,
               float* __restrict__ partg) {
    // 139264 B: loop uses first 131072 as LA[2]|LB[2]; epilogue reuses all as red[]
    __shared__ __align__(16) unsigned char smem[139264];
    __bf16* LAb = (__bf16*)smem;                    // LA[buf] = LAb + buf*16384
    __bf16* LBb = (__bf16*)(smem + 65536);          // LB[buf] = LBb + buf*16384
    float*  red = (float*)smem;                     // [256*2][68] f32 epilogue scratch

    int bid = blockIdx.x;
    int lgc = (bid & 7) * 128 + (bid >> 3);         // XCD-bijective (1024 % 8 == 0)
    int pm = lgc >> 2, pn = lgc & 3;
    const int row0 = pm * 256, col0 = pn * 256;

    int tid = threadIdx.x;
    int wid = tid >> 6, lane = tid & 63;
    int wr = wid >> 2, wc = wid & 3;
    int l15 = lane & 15, lq = lane >> 4;

    f32x4 acc[2][2][4][2] = {};
    float4 fa[4][2];                                // in-flight A (f32), T14 staging

    // issue A loads for K-tile kt (8x float4, pre-swizzled source addresses)
    #define LOAD_A(kt) do {                                                       \
        _Pragma("unroll")                                                         \
        for (int i = 0; i < 4; ++i) {                                             \
            int q = i * 512 + tid;                                                \
            int r = q >> 3, c = q & 7;                                            \
            int sc = (c ^ (r & 7)) * 8 + (kt) * 64;                               \
            const float* s0 = &enc[(size_t)(row0 + r) * HID + sc];                \
            fa[i][0] = *(const float4*)s0;                                        \
            fa[i][1] = *(const float4*)(s0 + 4);                                  \
        }                                                                         \
    } while (0)

    // convert + write A regs into LDS buf (linear dest; swizzle was on source)
    #define WRITE_A(buf) do {                                                     \
        _Pragma("unroll")                                                         \
        for (int i = 0; i < 4; ++i) {                                             \
            int q = i * 512 + tid;                                                \
            BF8 t;                                                                \
            t.h[0] = (__bf16)fa[i][0].x; t.h[1] = (__bf16)fa[i][0].y;             \
            t.h[2] = (__bf16)fa[i][0].z; t.h[3] = (__bf16)fa[i][0].w;             \
            t.h[4] = (__bf16)fa[i][1].x; t.h[5] = (__bf16)fa[i][1].y;             \
            t.h[6] = (__bf16)fa[i][1].z; t.h[7] = (__bf16)fa[i][1].w;             \
            *(BF8*)&LAb[(buf) * 16384 + q * 8] = t;                               \
        }                                                                         \
    } while (0)

    // B stage via lds-DMA (Bt is bf16 already; tiny 2MB matrix, L2-resident)
    #define STAGE_B(buf, kt) do {                                                 \
        _Pragma("unroll")                                                         \
        for (int i = 0; i < 4; ++i) {                                             \
            int q = i * 512 + tid;                                                \
            int r = q >> 3, c = q & 7;                                            \
            int sc = (c ^ (r & 7)) * 8 + (kt) * 64;                               \
            __builtin_amdgcn_global_load_lds(                                     \
                (glb_void*)(Bt + (size_t)(col0 + r) * HID + sc),                  \
                (lds_void*)(LBb + (buf) * 16384 + q * 8), 16, 0, 0);              \
        }                                                                         \
    } while (0)

    // prologue: tile 0
    LOAD_A(0);              // 8 vmem loads (oldest)
    STAGE_B(0, 0);          // 4 lds-DMA (younger)
    WRITE_A(0);             // data-dep wait => vmcnt(4): A done, B still in flight
    __syncthreads();        // drains vmcnt+lgkm: B DMA + A ds_writes complete

    int cur = 0;
    for (int kt = 0; kt < NKT; ++kt) {
        if (kt + 1 < NKT) {
            LOAD_A(kt + 1);             // issue early (T14): hides under ds_read+MFMA
            STAGE_B(cur ^ 1, kt + 1);
        }

        const __bf16* LAc = LAb + cur * 16384;
        const __bf16* LBc = LBb + cur * 16384;
        bf16x8 bfr[2][2][2];
        #pragma unroll
        for (int qb = 0; qb < 2; ++qb)
            #pragma unroll
            for (int n = 0; n < 2; ++n)
                #pragma unroll
                for (int kk = 0; kk < 2; ++kk) {
                    int r = qb * 128 + wc * 32 + n * 16 + l15;
                    bfr[qb][n][kk] = *(const bf16x8*)
                        &LBc[r * 64 + (((kk * 4 + lq) ^ (r & 7)) * 8)];
                }
        #pragma unroll
        for (int qa = 0; qa < 2; ++qa) {
            bf16x8 af[4][2];
            #pragma unroll
            for (int m = 0; m < 4; ++m)
                #pragma unroll
                for (int kk = 0; kk < 2; ++kk) {
                    int r = qa * 128 + wr * 64 + m * 16 + l15;
                    af[m][kk] = *(const bf16x8*)
                        &LAc[r * 64 + (((kk * 4 + lq) ^ (r & 7)) * 8)];
                }
            #pragma unroll
            for (int qb = 0; qb < 2; ++qb)
                #pragma unroll
                for (int m = 0; m < 4; ++m)
                    #pragma unroll
                    for (int n = 0; n < 2; ++n)
                        #pragma unroll
                        for (int kk = 0; kk < 2; ++kk)
                            acc[qa][qb][m][n] = __builtin_amdgcn_mfma_f32_16x16x32_bf16(
                                af[m][kk], bfr[qb][n][kk], acc[qa][qb][m][n], 0, 0, 0);
        }

        if (kt + 1 < NKT) WRITE_A(cur ^ 1);   // write late: cur^1 reads fenced by
                                              // previous iteration's barrier
        __syncthreads();    // also fences last LA/LB reads before red[] reuse
        cur ^= 1;
    }
    #undef LOAD_A
    #undef WRITE_A
    #undef STAGE_B

    // ---- epilogue: per-lane gelu+W2 partials -> LDS transpose -> tree-free sum --
    int b = row0 >> 11;
    float fcv[2][2], w2a[2][2], w2b[2][2];
    #pragma unroll
    for (int qb = 0; qb < 2; ++qb)
        #pragma unroll
        for (int n = 0; n < 2; ++n) {
            int h = col0 + qb * 128 + wc * 32 + n * 16 + l15;
            fcv[qb][n] = fc[b * HID + h];
            w2a[qb][n] = W2[h];
            w2b[qb][n] = W2[HID + h];
        }
    int e = wc * 16 + l15;                  // 0..63: which h-subgroup this lane covers
    #pragma unroll
    for (int qa = 0; qa < 2; ++qa)
        #pragma unroll
        for (int m = 0; m < 4; ++m)
            #pragma unroll
            for (int j = 0; j < 4; ++j) {
                int rloc = qa * 128 + wr * 64 + m * 16 + lq * 4 + j;
                float p0 = 0.f, p1 = 0.f;
                #pragma unroll
                for (int qb = 0; qb < 2; ++qb)
                    #pragma unroll
                    for (int n = 0; n < 2; ++n) {
                        float g = gelu_bf(acc[qa][qb][m][n][j] + fcv[qb][n]);
                        p0 += g * w2a[qb][n];
                        p1 += g * w2b[qb][n];
                    }
                red[(rloc * 2 + 0) * 68 + e] = p0;
                red[(rloc * 2 + 1) * 68 + e] = p1;
            }
    __syncthreads();
    {   // one (row, class) per thread: sum 64 partials via 16 aligned b128 reads
        const f32x4* rp = (const f32x4*)&red[tid * 68];
        f32x4 sv = {0.f, 0.f, 0.f, 0.f};
        #pragma unroll
        for (int i = 0; i < 16; ++i) sv += rp[i];
        float s = sv[0] + sv[1] + sv[2] + sv[3];
        int row = tid >> 1, c = tid & 1;
        partg[((size_t)pn * MROWS + row0 + row) * 2 + c] = s;
    }
}

// ---------------- FALLBACK GEMM (atomics path, used only if ws too small) -------
__global__ __launch_bounds__(256, 2)
void sr_gemm_fused(const float* __restrict__ enc, const __bf16* __restrict__ Bt,
                   const float* __restrict__ fc, const float* __restrict__ W2,
                   float* __restrict__ logits) {
    __shared__ __bf16 As[128 * 64];
    __shared__ __bf16 Bs[128 * 64];

    int bid = blockIdx.x;
    int logical = (bid & 7) * 512 + (bid >> 3);
    int pm = logical >> 3;
    int pn = logical & 7;

    int tid = threadIdx.x;
    int wid = tid >> 6, lane = tid & 63;
    int wm = wid >> 1, wn = wid & 1;

    const int row0 = pm * 128;
    const int col0 = pn * 128;

    f32x4 acc[4][4] = {};

    for (int kt = 0; kt < 16; ++kt) {
        int k0 = kt * 64;
        #pragma unroll
        for (int i = 0; i < 4; ++i) {
            int q = i * 256 + tid;
            int r = q >> 3;
            int cb = (q & 7) * 8;
            const __bf16* src = Bt + (size_t)(col0 + r) * 1024 + k0 + cb;
            __builtin_amdgcn_global_load_lds((glb_void*)src, (lds_void*)&Bs[q * 8], 16, 0, 0);
        }
        #pragma unroll
        for (int pp = 0; pp < 4; ++pp) {
            int e = pp * 2048 + tid * 8;
            int r = e >> 6, c = e & 63;
            const float* src = enc + (size_t)(row0 + r) * 1024 + k0 + c;
            float4 f0 = *(const float4*)src;
            float4 f1 = *(const float4*)(src + 4);
            BF8 t;
            t.h[0] = (__bf16)f0.x; t.h[1] = (__bf16)f0.y;
            t.h[2] = (__bf16)f0.z; t.h[3] = (__bf16)f0.w;
            t.h[4] = (__bf16)f1.x; t.h[5] = (__bf16)f1.y;
            t.h[6] = (__bf16)f1.z; t.h[7] = (__bf16)f1.w;
            *(BF8*)&As[r * 64 + c] = t;
        }
        __syncthreads();
        int lrow = lane & 15;
        int ak = (lane >> 4) * 8;
        #pragma unroll
        for (int kk = 0; kk < 2; ++kk) {
            bf16x8 a[4], b[4];
            #pragma unroll
            for (int m = 0; m < 4; ++m)
                a[m] = *(const bf16x8*)&As[(wm * 64 + m * 16 + lrow) * 64 + kk * 32 + ak];
            #pragma unroll
            for (int n = 0; n < 4; ++n)
                b[n] = *(const bf16x8*)&Bs[(wn * 64 + n * 16 + lrow) * 64 + kk * 32 + ak];
            #pragma unroll
            for (int m = 0; m < 4; ++m)
                #pragma unroll
                for (int n = 0; n < 4; ++n)
                    acc[m][n] = __builtin_amdgcn_mfma_f32_16x16x32_bf16(a[m], b[n], acc[m][n], 0, 0, 0);
        }
        __syncthreads();
    }

    int bidx = row0 >> 11;
    float fcv[4], w2a[4], w2b[4];
    #pragma unroll
    for (int n = 0; n < 4; ++n) {
        int h = col0 + wn * 64 + n * 16 + (lane & 15);
        fcv[n] = fc[bidx * HID + h];
        w2a[n] = W2[h];
        w2b[n] = W2[HID + h];
    }
    #pragma unroll
    for (int m = 0; m < 4; ++m) {
        int rbase = row0 + wm * 64 + m * 16 + (lane >> 4) * 4;
        #pragma unroll
        for (int j = 0; j < 4; ++j) {
            float p0 = 0.f, p1 = 0.f;
            #pragma unroll
            for (int n = 0; n < 4; ++n) {
                float g = gelu_bf(acc[m][n][j] + fcv[n]);
                p0 += g * w2a[n];
                p1 += g * w2b[n];
            }
            #pragma unroll
            for (int off = 1; off < 16; off <<= 1) {
                p0 += __shfl_xor(p0, off);
                p1 += __shfl_xor(p1, off);
            }
            if ((lane & 15) == 0) {
                int rg = rbase + j;
                atomicAdd(&logits[rg * 2 + 0], p0);
                atomicAdd(&logits[rg * 2 + 1], p1);
            }
        }
    }
}

// ---------------- loss from partials: logits = b2 + sum_pn partg; CE ------------
__global__ void sr_loss_pg(const int* __restrict__ lab, const float* __restrict__ partg,
                           const float* __restrict__ b2, float* __restrict__ logits,
                           float* __restrict__ mask_out, float* __restrict__ sl,
                           float* __restrict__ validv) {
    int b = blockIdx.x;
    int tid = threadIdx.x;
    float b20 = b2[0], b21 = b2[1];
    float lsum = 0.f; int lcnt = 0;
    for (int s = tid; s < SEQ; s += 256) {
        size_t row = (size_t)b * SEQ + s;
        float l0 = b20, l1 = b21;
        #pragma unroll
        for (int q = 0; q < 4; ++q) {
            l0 += partg[((size_t)q * MROWS + row) * 2 + 0];
            l1 += partg[((size_t)q * MROWS + row) * 2 + 1];
        }
        logits[row * 2 + 0] = l0;
        logits[row * 2 + 1] = l1;
        int l = lab[row];
        bool hdr = (l == 0) || (l == 1);
        mask_out[row] = hdr ? 1.0f : 0.0f;
        if (hdr) {
            float mx = fmaxf(l0, l1);
            float lse = mx + logf(expf(l0 - mx) + expf(l1 - mx));
            lsum += lse - (l == 0 ? l0 : l1);
            lcnt++;
        }
    }
    #pragma unroll
    for (int off = 32; off; off >>= 1) {
        lsum += __shfl_down(lsum, off);
        lcnt += __shfl_down(lcnt, off);
    }
    __shared__ float wsum[4];
    __shared__ int wcnt[4];
    int wid = tid >> 6, lane = tid & 63;
    if (lane == 0) { wsum[wid] = lsum; wcnt[wid] = lcnt; }
    __syncthreads();
    if (tid == 0) {
        float S = wsum[0] + wsum[1] + wsum[2] + wsum[3];
        int C = wcnt[0] + wcnt[1] + wcnt[2] + wcnt[3];
        sl[b] = (C > 0) ? S / (float)C : 0.0f;
        validv[b] = (C > 0) ? 1.0f : 0.0f;
    }
}

// ---------------- loss reading logits directly (FALLBACK path) ------------------
__global__ void sr_loss(const int* __restrict__ lab, const float* __restrict__ logits,
                        float* __restrict__ mask_out, float* __restrict__ sl,
                        float* __restrict__ validv) {
    int b = blockIdx.x;
    int tid = threadIdx.x;
    float lsum = 0.f; int lcnt = 0;
    for (int s = tid; s < SEQ; s += 256) {
        int l = lab[b * SEQ + s];
        bool hdr = (l == 0) || (l == 1);
        mask_out[b * SEQ + s] = hdr ? 1.0f : 0.0f;
        if (hdr) {
            float l0 = logits[(b * SEQ + s) * 2];
            float l1 = logits[(b * SEQ + s) * 2 + 1];
            float mx = fmaxf(l0, l1);
            float lse = mx + logf(expf(l0 - mx) + expf(l1 - mx));
            lsum += lse - (l == 0 ? l0 : l1);
            lcnt++;
        }
    }
    #pragma unroll
    for (int off = 32; off; off >>= 1) {
        lsum += __shfl_down(lsum, off);
        lcnt += __shfl_down(lcnt, off);
    }
    __shared__ float wsum[4];
    __shared__ int wcnt[4];
    int wid = tid >> 6, lane = tid & 63;
    if (lane == 0) { wsum[wid] = lsum; wcnt[wid] = lcnt; }
    __syncthreads();
    if (tid == 0) {
        float S = wsum[0] + wsum[1] + wsum[2] + wsum[3];
        int C = wcnt[0] + wcnt[1] + wcnt[2] + wcnt[3];
        sl[b] = (C > 0) ? S / (float)C : 0.0f;
        validv[b] = (C > 0) ? 1.0f : 0.0f;
    }
}

__global__ void sr_final(const float* __restrict__ sl, const float* __restrict__ validv,
                         float* __restrict__ out) {
    if (threadIdx.x == 0) {
        float s = 0.f, v = 0.f;
        for (int b = 0; b < NB; ++b) { s += sl[b]; v += validv[b]; }
        out[0] = s / (v + 1e-6f);
    }
}

extern "C" void kernel_launch(void* const* d_in, const int* in_sizes, int n_in,
                              void* d_out, int out_size, void* d_ws, size_t ws_size,
                              hipStream_t stream) {
    const float* enc = (const float*)d_in[0];
    const int*   lab = (const int*)d_in[1];
    const float* W1  = (const float*)d_in[2];
    const float* b1  = (const float*)d_in[3];
    const float* W2  = (const float*)d_in[4];
    const float* b2  = (const float*)d_in[5];

    float* out     = (float*)d_out;
    float* loss    = out;
    float* logits  = out + 1;
    float* maskout = out + 1 + MROWS * 2;

    float* ws     = (float*)d_ws;
    float* femb   = ws;                            // 32768 f32
    float* fc     = ws + 32768;                    // 32768 f32
    float* sl     = ws + 65536;                    // 32
    float* validv = ws + 65568;                    // 32
    float* partg  = ws + 65600;                    // 524288 f32 (2 MB)
    __bf16* Bt    = (__bf16*)(ws + 65600 + 2 * 524288);  // 2 MB

    const size_t need = (65600u + 2u * 524288u) * 4u + (size_t)HID * HID * 2u;

    sr_conv_w1<<<1024, 256, 0, stream>>>(W1, Bt);
    sr_femb<<<32, 256, 0, stream>>>(enc, lab, femb);
    sr_fc<<<512, 256, 0, stream>>>(femb, W1, b1, fc);

    if (ws_size >= need) {
        sr_gemm11<<<1024, 512, 0, stream>>>(enc, Bt, fc, W2, partg);
        sr_loss_pg<<<32, 256, 0, stream>>>(lab, partg, b2, logits, maskout, sl, validv);
    } else {
        sr_init_logits<<<512, 256, 0, stream>>>(logits, b2);
        sr_gemm_fused<<<4096, 256, 0, stream>>>(enc, Bt, fc, W2, logits);
        sr_loss<<<32, 256, 0, stream>>>(lab, logits, maskout, sl, validv);
    }

    sr_final<<<1, 64, 0, stream>>>(sl, validv, loss);
}

// Round 4
// 256.543 us; speedup vs baseline: 1.0306x; 1.0261x over previous
//
#include <hip/hip_runtime.h>
#include <math.h>

// Problem: B=32, S=2048, H=1024
//   d_out (float): [0] loss | [1..131073) logits (32,2048,2) | [131073..196609) header_mask
//
// R13: exact R9 pipeline (R12's post-barrier drain was UNSOUND: vmcnt is
// per-wave, so draining after s_barrier lets a wave read LDS regions whose
// DMAs were issued by OTHER waves and are still in flight -> NaN).
// Diagnosis from counters: per tile, LDS pipe ~2800cy and MFMA ~2483cy run
// SERIALIZED (measured 4650cy/tile): 1 block/CU lockstep + all-loads-first
// compiler scheduling = read flood then MFMA burst. The DMA drain is free
// (issued a full compute-phase earlier). Fix: T19 sched_group_barrier spec
// to interleave ds_reads into the MFMA stream (DMA x8, ds_read x12,
// {MFMA4,ds1}x4, MFMA16, ds8, MFMA32). Compile-time only; data deps still
// hardware-enforced -> bit-identical results. STAGE made branchless
// (clamped kt) so the tile body is a single BB for the SGB spec.

typedef __bf16 bf16x8 __attribute__((ext_vector_type(8)));
typedef float f32x4 __attribute__((ext_vector_type(4)));

struct alignas(16) BF8 { __bf16 h[8]; };
struct alignas(8)  BF4 { __bf16 h[4]; };

typedef const __attribute__((address_space(1))) void glb_void;
typedef __attribute__((address_space(3))) void lds_void;

#define SEQ 2048
#define NB  32
#define HID 1024
#define MROWS (NB * SEQ)          // 65536
#define NKT 16                    // K tiles of 64

// branch-free exact-GELU via A&S 7.1.26 erf approximation (|eps| < 1.5e-7)
__device__ __forceinline__ float gelu_bf(float x) {
    float z  = 0.70710678118f * x;
    float az = fabsf(z);
    float t  = __builtin_amdgcn_rcpf(fmaf(0.3275911f, az, 1.0f));
    float poly = fmaf(fmaf(fmaf(fmaf(1.061405429f, t, -1.453152027f), t,
                         1.421413741f), t, -0.284496736f), t, 0.254829592f) * t;
    float ex = __expf(-az * az);
    float er = copysignf(fmaf(-poly, ex, 1.0f), z);
    return 0.5f * x * (1.0f + er);
}

// ---------------- init logits with b2 (FALLBACK path only) ----------------------
__global__ void sr_init_logits(float* __restrict__ logits, const float* __restrict__ b2) {
    int i = blockIdx.x * 256 + threadIdx.x;
    if (i < MROWS * 2) logits[i] = b2[i & 1];
}

// ---------------- W1 first half -> bf16 -----------------------------------------
__global__ void sr_conv_w1(const float* __restrict__ W1, __bf16* __restrict__ Bt) {
    int gid = blockIdx.x * 256 + threadIdx.x;
    int h = gid >> 8;
    int kb = (gid & 255) * 4;
    float4 v = *(const float4*)&W1[(size_t)h * 2048 + kb];
    BF4 o;
    o.h[0] = (__bf16)v.x; o.h[1] = (__bf16)v.y; o.h[2] = (__bf16)v.z; o.h[3] = (__bf16)v.w;
    *(BF4*)&Bt[(size_t)h * 1024 + kb] = o;
}

// ---------------- enc f32 -> bf16 (Ab) ------------------------------------------
__global__ void sr_conv_enc(const float* __restrict__ enc, __bf16* __restrict__ Ab) {
    size_t i = ((size_t)blockIdx.x * 256 + threadIdx.x) * 8;
    float4 v0 = *(const float4*)&enc[i];
    float4 v1 = *(const float4*)&enc[i + 4];
    BF8 t;
    t.h[0] = (__bf16)v0.x; t.h[1] = (__bf16)v0.y;
    t.h[2] = (__bf16)v0.z; t.h[3] = (__bf16)v0.w;
    t.h[4] = (__bf16)v1.x; t.h[5] = (__bf16)v1.y;
    t.h[6] = (__bf16)v1.z; t.h[7] = (__bf16)v1.w;
    *(BF8*)&Ab[i] = t;
}

// ---------------- formula embedding: index-gather (labels scanned, not enc) -----
__global__ void sr_femb(const float* __restrict__ enc, const int* __restrict__ lab,
                        float* __restrict__ femb) {
    __shared__ int cnt;
    __shared__ int idl[64];                 // plenty: exactly 1 hit/sample by construction
    int b = blockIdx.x;
    int tid = threadIdx.x;
    if (tid == 0) cnt = 0;
    __syncthreads();
    for (int s = tid; s < SEQ; s += 256)
        if (lab[b * SEQ + s] == 2) {
            int p = atomicAdd(&cnt, 1);
            if (p < 64) idl[p] = s;
        }
    __syncthreads();
    float4 a = {0.f, 0.f, 0.f, 0.f};
    int n = cnt < 64 ? cnt : 64;
    for (int i = 0; i < n; ++i) {
        float4 v = *(const float4*)&enc[((size_t)b * SEQ + idl[i]) * HID + tid * 4];
        a.x += v.x; a.y += v.y; a.z += v.z; a.w += v.w;
    }
    *(float4*)&femb[b * HID + tid * 4] = a;
}

// ---------------- fc[b,h] = b1[h] + femb[b,:] . W1[h,1024:2048] -----------------
__global__ void sr_fc(const float* __restrict__ femb, const float* __restrict__ W1,
                      const float* __restrict__ b1, float* __restrict__ fcout) {
    int gw = (blockIdx.x * 256 + threadIdx.x) >> 6;
    int lane = threadIdx.x & 63;
    for (int i = 0; i < 16; ++i) {
        int d = gw * 16 + i;
        int b = d >> 10, h = d & 1023;
        const float* fe = femb + b * HID;
        const float* wr = W1 + (size_t)h * 2048 + 1024;
        float p = 0.f;
        #pragma unroll
        for (int t = 0; t < 16; ++t) {
            int k = lane + t * 64;
            p += fe[k] * wr[k];
        }
        #pragma unroll
        for (int off = 32; off; off >>= 1) p += __shfl_down(p, off);
        if (lane == 0) fcout[d] = p + b1[h];
    }
}

// ---------------- PRIMARY: 256^2 2-phase GEMM + SGB interleave ------------------
__global__ __launch_bounds__(512, 2)
void sr_gemm13(const __bf16* __restrict__ Ab, const __bf16* __restrict__ Bt,
               const float* __restrict__ fc, const float* __restrict__ W2,
               float* __restrict__ partg) {
    // 139264 B: loop uses first 131072 as LA[2]|LB[2]; epilogue reuses all as red[]
    __shared__ __align__(16) unsigned char smem[139264];
    __bf16* LAb = (__bf16*)smem;                    // LA[buf] = LAb + buf*16384
    __bf16* LBb = (__bf16*)(smem + 65536);          // LB[buf] = LBb + buf*16384
    float*  red = (float*)smem;                     // [256*2][68] f32 epilogue scratch

    int bid = blockIdx.x;
    int lgc = (bid & 7) * 128 + (bid >> 3);         // XCD-bijective (1024 % 8 == 0)
    int pm = lgc >> 2, pn = lgc & 3;
    const int row0 = pm * 256, col0 = pn * 256;

    int tid = threadIdx.x;
    int wid = tid >> 6, lane = tid & 63;
    int wr = wid >> 2, wc = wid & 3;
    int l15 = lane & 15, lq = lane >> 4;

    f32x4 acc[2][2][4][2] = {};

    #define STAGE(buf, kt) do {                                                   \
        _Pragma("unroll")                                                         \
        for (int i = 0; i < 4; ++i) {                                             \
            int q = i * 512 + tid;                                                \
            int r = q >> 3, c = q & 7;                                            \
            int sc = (c ^ (r & 7)) * 8 + (kt) * 64;                               \
            __builtin_amdgcn_global_load_lds(                                     \
                (glb_void*)(Ab + (size_t)(row0 + r) * HID + sc),                  \
                (lds_void*)(LAb + (buf) * 16384 + q * 8), 16, 0, 0);              \
            __builtin_amdgcn_global_load_lds(                                     \
                (glb_void*)(Bt + (size_t)(col0 + r) * HID + sc),                  \
                (lds_void*)(LBb + (buf) * 16384 + q * 8), 16, 0, 0);              \
        }                                                                         \
    } while (0)

    STAGE(0, 0);
    __syncthreads();

    int cur = 0;
    for (int kt = 0; kt < NKT; ++kt) {
        // branchless clamped prefetch: kt=15 re-stages tile 15 into the dead
        // buffer (L2-hot, never read; drained by the final __syncthreads).
        int ktn = (kt + 1 < NKT) ? kt + 1 : NKT - 1;
        STAGE(cur ^ 1, ktn);

        const __bf16* LAc = LAb + cur * 16384;
        const __bf16* LBc = LBb + cur * 16384;
        bf16x8 bfr[2][2][2];
        #pragma unroll
        for (int qb = 0; qb < 2; ++qb)
            #pragma unroll
            for (int n = 0; n < 2; ++n)
                #pragma unroll
                for (int kk = 0; kk < 2; ++kk) {
                    int r = qb * 128 + wc * 32 + n * 16 + l15;
                    bfr[qb][n][kk] = *(const bf16x8*)
                        &LBc[r * 64 + (((kk * 4 + lq) ^ (r & 7)) * 8)];
                }
        #pragma unroll
        for (int qa = 0; qa < 2; ++qa) {
            bf16x8 af[4][2];
            #pragma unroll
            for (int m = 0; m < 4; ++m)
                #pragma unroll
                for (int kk = 0; kk < 2; ++kk) {
                    int r = qa * 128 + wr * 64 + m * 16 + l15;
                    af[m][kk] = *(const bf16x8*)
                        &LAc[r * 64 + (((kk * 4 + lq) ^ (r & 7)) * 8)];
                }
            #pragma unroll
            for (int qb = 0; qb < 2; ++qb)
                #pragma unroll
                for (int m = 0; m < 4; ++m)
                    #pragma unroll
                    for (int n = 0; n < 2; ++n)
                        #pragma unroll
                        for (int kk = 0; kk < 2; ++kk)
                            acc[qa][qb][m][n] = __builtin_amdgcn_mfma_f32_16x16x32_bf16(
                                af[m][kk], bfr[qb][n][kk], acc[qa][qb][m][n], 0, 0, 0);
        }

        // T19 schedule spec for this tile body (compile-time; deps still
        // enforced by HW waitcnt). Classes: 0x070 VMEM, 0x100 DS_READ, 0x8 MFMA.
        // Intent: DMAs first, then 12 reads (bfr-qb0 + af-qa0), MM(0,0)
        // interleaved 4:1 with bfr-qb1 reads, MM(0,1), af-qa1 reads, MM(1,*).
        __builtin_amdgcn_sched_group_barrier(0x070, 8, 0);
        __builtin_amdgcn_sched_group_barrier(0x100, 12, 0);
        __builtin_amdgcn_sched_group_barrier(0x008, 4, 0);
        __builtin_amdgcn_sched_group_barrier(0x100, 1, 0);
        __builtin_amdgcn_sched_group_barrier(0x008, 4, 0);
        __builtin_amdgcn_sched_group_barrier(0x100, 1, 0);
        __builtin_amdgcn_sched_group_barrier(0x008, 4, 0);
        __builtin_amdgcn_sched_group_barrier(0x100, 1, 0);
        __builtin_amdgcn_sched_group_barrier(0x008, 4, 0);
        __builtin_amdgcn_sched_group_barrier(0x100, 1, 0);
        __builtin_amdgcn_sched_group_barrier(0x008, 16, 0);
        __builtin_amdgcn_sched_group_barrier(0x100, 8, 0);
        __builtin_amdgcn_sched_group_barrier(0x008, 32, 0);

        __syncthreads();    // per-wave vmcnt(0)+lgkmcnt(0) then barrier (sound)
        cur ^= 1;
    }
    #undef STAGE

    // ---- epilogue: per-lane gelu+W2 partials -> LDS transpose -> tree-free sum --
    int b = row0 >> 11;
    float fcv[2][2], w2a[2][2], w2b[2][2];
    #pragma unroll
    for (int qb = 0; qb < 2; ++qb)
        #pragma unroll
        for (int n = 0; n < 2; ++n) {
            int h = col0 + qb * 128 + wc * 32 + n * 16 + l15;
            fcv[qb][n] = fc[b * HID + h];
            w2a[qb][n] = W2[h];
            w2b[qb][n] = W2[HID + h];
        }
    int e = wc * 16 + l15;                  // 0..63: which h-subgroup this lane covers
    #pragma unroll
    for (int qa = 0; qa < 2; ++qa)
        #pragma unroll
        for (int m = 0; m < 4; ++m)
            #pragma unroll
            for (int j = 0; j < 4; ++j) {
                int rloc = qa * 128 + wr * 64 + m * 16 + lq * 4 + j;
                float p0 = 0.f, p1 = 0.f;
                #pragma unroll
                for (int qb = 0; qb < 2; ++qb)
                    #pragma unroll
                    for (int n = 0; n < 2; ++n) {
                        float g = gelu_bf(acc[qa][qb][m][n][j] + fcv[qb][n]);
                        p0 += g * w2a[qb][n];
                        p1 += g * w2b[qb][n];
                    }
                red[(rloc * 2 + 0) * 68 + e] = p0;
                red[(rloc * 2 + 1) * 68 + e] = p1;
            }
    __syncthreads();
    {   // one (row, class) per thread: sum 64 partials via 16 aligned b128 reads
        const f32x4* rp = (const f32x4*)&red[tid * 68];
        f32x4 sv = {0.f, 0.f, 0.f, 0.f};
        #pragma unroll
        for (int i = 0; i < 16; ++i) sv += rp[i];
        float s = sv[0] + sv[1] + sv[2] + sv[3];
        int row = tid >> 1, c = tid & 1;
        partg[((size_t)pn * MROWS + row0 + row) * 2 + c] = s;
    }
}

// ---------------- FALLBACK GEMM (atomics path, used only if ws too small) -------
__global__ __launch_bounds__(256, 2)
void sr_gemm_fused(const float* __restrict__ enc, const __bf16* __restrict__ Bt,
                   const float* __restrict__ fc, const float* __restrict__ W2,
                   float* __restrict__ logits) {
    __shared__ __bf16 As[128 * 64];
    __shared__ __bf16 Bs[128 * 64];

    int bid = blockIdx.x;
    int logical = (bid & 7) * 512 + (bid >> 3);
    int pm = logical >> 3;
    int pn = logical & 7;

    int tid = threadIdx.x;
    int wid = tid >> 6, lane = tid & 63;
    int wm = wid >> 1, wn = wid & 1;

    const int row0 = pm * 128;
    const int col0 = pn * 128;

    f32x4 acc[4][4] = {};

    for (int kt = 0; kt < 16; ++kt) {
        int k0 = kt * 64;
        #pragma unroll
        for (int i = 0; i < 4; ++i) {
            int q = i * 256 + tid;
            int r = q >> 3;
            int cb = (q & 7) * 8;
            const __bf16* src = Bt + (size_t)(col0 + r) * 1024 + k0 + cb;
            __builtin_amdgcn_global_load_lds((glb_void*)src, (lds_void*)&Bs[q * 8], 16, 0, 0);
        }
        #pragma unroll
        for (int pp = 0; pp < 4; ++pp) {
            int e = pp * 2048 + tid * 8;
            int r = e >> 6, c = e & 63;
            const float* src = enc + (size_t)(row0 + r) * 1024 + k0 + c;
            float4 f0 = *(const float4*)src;
            float4 f1 = *(const float4*)(src + 4);
            BF8 t;
            t.h[0] = (__bf16)f0.x; t.h[1] = (__bf16)f0.y;
            t.h[2] = (__bf16)f0.z; t.h[3] = (__bf16)f0.w;
            t.h[4] = (__bf16)f1.x; t.h[5] = (__bf16)f1.y;
            t.h[6] = (__bf16)f1.z; t.h[7] = (__bf16)f1.w;
            *(BF8*)&As[r * 64 + c] = t;
        }
        __syncthreads();
        int lrow = lane & 15;
        int ak = (lane >> 4) * 8;
        #pragma unroll
        for (int kk = 0; kk < 2; ++kk) {
            bf16x8 a[4], b[4];
            #pragma unroll
            for (int m = 0; m < 4; ++m)
                a[m] = *(const bf16x8*)&As[(wm * 64 + m * 16 + lrow) * 64 + kk * 32 + ak];
            #pragma unroll
            for (int n = 0; n < 4; ++n)
                b[n] = *(const bf16x8*)&Bs[(wn * 64 + n * 16 + lrow) * 64 + kk * 32 + ak];
            #pragma unroll
            for (int m = 0; m < 4; ++m)
                #pragma unroll
                for (int n = 0; n < 4; ++n)
                    acc[m][n] = __builtin_amdgcn_mfma_f32_16x16x32_bf16(a[m], b[n], acc[m][n], 0, 0, 0);
        }
        __syncthreads();
    }

    int bidx = row0 >> 11;
    float fcv[4], w2a[4], w2b[4];
    #pragma unroll
    for (int n = 0; n < 4; ++n) {
        int h = col0 + wn * 64 + n * 16 + (lane & 15);
        fcv[n] = fc[bidx * HID + h];
        w2a[n] = W2[h];
        w2b[n] = W2[HID + h];
    }
    #pragma unroll
    for (int m = 0; m < 4; ++m) {
        int rbase = row0 + wm * 64 + m * 16 + (lane >> 4) * 4;
        #pragma unroll
        for (int j = 0; j < 4; ++j) {
            float p0 = 0.f, p1 = 0.f;
            #pragma unroll
            for (int n = 0; n < 4; ++n) {
                float g = gelu_bf(acc[m][n][j] + fcv[n]);
                p0 += g * w2a[n];
                p1 += g * w2b[n];
            }
            #pragma unroll
            for (int off = 1; off < 16; off <<= 1) {
                p0 += __shfl_xor(p0, off);
                p1 += __shfl_xor(p1, off);
            }
            if ((lane & 15) == 0) {
                int rg = rbase + j;
                atomicAdd(&logits[rg * 2 + 0], p0);
                atomicAdd(&logits[rg * 2 + 1], p1);
            }
        }
    }
}

// ---------------- loss from partials: logits = b2 + sum_pn partg; CE ------------
__global__ void sr_loss_pg(const int* __restrict__ lab, const float* __restrict__ partg,
                           const float* __restrict__ b2, float* __restrict__ logits,
                           float* __restrict__ mask_out, float* __restrict__ sl,
                           float* __restrict__ validv) {
    int b = blockIdx.x;
    int tid = threadIdx.x;
    float b20 = b2[0], b21 = b2[1];
    float lsum = 0.f; int lcnt = 0;
    for (int s = tid; s < SEQ; s += 256) {
        size_t row = (size_t)b * SEQ + s;
        float l0 = b20, l1 = b21;
        #pragma unroll
        for (int q = 0; q < 4; ++q) {
            l0 += partg[((size_t)q * MROWS + row) * 2 + 0];
            l1 += partg[((size_t)q * MROWS + row) * 2 + 1];
        }
        logits[row * 2 + 0] = l0;
        logits[row * 2 + 1] = l1;
        int l = lab[row];
        bool hdr = (l == 0) || (l == 1);
        mask_out[row] = hdr ? 1.0f : 0.0f;
        if (hdr) {
            float mx = fmaxf(l0, l1);
            float lse = mx + logf(expf(l0 - mx) + expf(l1 - mx));
            lsum += lse - (l == 0 ? l0 : l1);
            lcnt++;
        }
    }
    #pragma unroll
    for (int off = 32; off; off >>= 1) {
        lsum += __shfl_down(lsum, off);
        lcnt += __shfl_down(lcnt, off);
    }
    __shared__ float wsum[4];
    __shared__ int wcnt[4];
    int wid = tid >> 6, lane = tid & 63;
    if (lane == 0) { wsum[wid] = lsum; wcnt[wid] = lcnt; }
    __syncthreads();
    if (tid == 0) {
        float S = wsum[0] + wsum[1] + wsum[2] + wsum[3];
        int C = wcnt[0] + wcnt[1] + wcnt[2] + wcnt[3];
        sl[b] = (C > 0) ? S / (float)C : 0.0f;
        validv[b] = (C > 0) ? 1.0f : 0.0f;
    }
}

// ---------------- loss reading logits directly (FALLBACK path) ------------------
__global__ void sr_loss(const int* __restrict__ lab, const float* __restrict__ logits,
                        float* __restrict__ mask_out, float* __restrict__ sl,
                        float* __restrict__ validv) {
    int b = blockIdx.x;
    int tid = threadIdx.x;
    float lsum = 0.f; int lcnt = 0;
    for (int s = tid; s < SEQ; s += 256) {
        int l = lab[b * SEQ + s];
        bool hdr = (l == 0) || (l == 1);
        mask_out[b * SEQ + s] = hdr ? 1.0f : 0.0f;
        if (hdr) {
            float l0 = logits[(b * SEQ + s) * 2];
            float l1 = logits[(b * SEQ + s) * 2 + 1];
            float mx = fmaxf(l0, l1);
            float lse = mx + logf(expf(l0 - mx) + expf(l1 - mx));
            lsum += lse - (l == 0 ? l0 : l1);
            lcnt++;
        }
    }
    #pragma unroll
    for (int off = 32; off; off >>= 1) {
        lsum += __shfl_down(lsum, off);
        lcnt += __shfl_down(lcnt, off);
    }
    __shared__ float wsum[4];
    __shared__ int wcnt[4];
    int wid = tid >> 6, lane = tid & 63;
    if (lane == 0) { wsum[wid] = lsum; wcnt[wid] = lcnt; }
    __syncthreads();
    if (tid == 0) {
        float S = wsum[0] + wsum[1] + wsum[2] + wsum[3];
        int C = wcnt[0] + wcnt[1] + wcnt[2] + wcnt[3];
        sl[b] = (C > 0) ? S / (float)C : 0.0f;
        validv[b] = (C > 0) ? 1.0f : 0.0f;
    }
}

__global__ void sr_final(const float* __restrict__ sl, const float* __restrict__ validv,
                         float* __restrict__ out) {
    if (threadIdx.x == 0) {
        float s = 0.f, v = 0.f;
        for (int b = 0; b < NB; ++b) { s += sl[b]; v += validv[b]; }
        out[0] = s / (v + 1e-6f);
    }
}

extern "C" void kernel_launch(void* const* d_in, const int* in_sizes, int n_in,
                              void* d_out, int out_size, void* d_ws, size_t ws_size,
                              hipStream_t stream) {
    const float* enc = (const float*)d_in[0];
    const int*   lab = (const int*)d_in[1];
    const float* W1  = (const float*)d_in[2];
    const float* b1  = (const float*)d_in[3];
    const float* W2  = (const float*)d_in[4];
    const float* b2  = (const float*)d_in[5];

    float* out     = (float*)d_out;
    float* loss    = out;
    float* logits  = out + 1;
    float* maskout = out + 1 + MROWS * 2;

    float* ws     = (float*)d_ws;
    float* femb   = ws;                            // 32768 f32
    float* fc     = ws + 32768;                    // 32768 f32
    float* sl     = ws + 65536;                    // 32
    float* validv = ws + 65568;                    // 32
    float* partg  = ws + 65600;                    // 524288 f32 (2 MB)
    __bf16* Bt    = (__bf16*)(ws + 65600 + 2 * 524288);  // 2 MB
    __bf16* Ab    = Bt + (size_t)HID * HID;              // 134.2 MB

    const size_t need = (65600u + 2u * 524288u) * 4u + (size_t)HID * HID * 2u
                      + (size_t)MROWS * HID * 2u;

    sr_conv_w1<<<1024, 256, 0, stream>>>(W1, Bt);
    sr_femb<<<32, 256, 0, stream>>>(enc, lab, femb);
    sr_fc<<<512, 256, 0, stream>>>(femb, W1, b1, fc);

    if (ws_size >= need) {
        sr_conv_enc<<<32768, 256, 0, stream>>>(enc, Ab);
        sr_gemm13<<<1024, 512, 0, stream>>>(Ab, Bt, fc, W2, partg);
        sr_loss_pg<<<32, 256, 0, stream>>>(lab, partg, b2, logits, maskout, sl, validv);
    } else {
        sr_init_logits<<<512, 256, 0, stream>>>(logits, b2);
        sr_gemm_fused<<<4096, 256, 0, stream>>>(enc, Bt, fc, W2, logits);
        sr_loss<<<32, 256, 0, stream>>>(lab, logits, maskout, sl, validv);
    }

    sr_final<<<1, 64, 0, stream>>>(sl, validv, loss);
}

// Round 5
// 254.859 us; speedup vs baseline: 1.0374x; 1.0066x over previous
//
#include <hip/hip_runtime.h>
#include <math.h>

// Problem: B=32, S=2048, H=1024
//   d_out (float): [0] loss | [1..131073) logits (32,2048,2) | [131073..196609) header_mask
//
// R14: schedule-level attacks (R10 8-phase, R12 counted-vmcnt, R13 SGB) all
// failed or were null -> the R9 instruction stream stays. The counter that
// matters: OccupancyPercent 21% = 2 waves/SIMD (512-thr block, 139KB LDS = 1
// block/CU). The loop's read->MFMA convoy has no sibling waves to fill it
// (m114 overlap mechanism starved). Fix: 1024-thread block, 16 waves, 4x4
// wave grid, 64x64 output/wave (acc 128->64 f32/lane so 16 waves fit at
// <=128 VGPR, forced by __launch_bounds__(1024,4)). Same tile, same LDS
// layout/swizzle, same K/kk accumulation order -> numerically identical GEMM.
// Epilogue gets 2x threads (64 gelu/thread, split final reduce + shfl_xor).

typedef __bf16 bf16x8 __attribute__((ext_vector_type(8)));
typedef float f32x4 __attribute__((ext_vector_type(4)));

struct alignas(16) BF8 { __bf16 h[8]; };
struct alignas(8)  BF4 { __bf16 h[4]; };

typedef const __attribute__((address_space(1))) void glb_void;
typedef __attribute__((address_space(3))) void lds_void;

#define SEQ 2048
#define NB  32
#define HID 1024
#define MROWS (NB * SEQ)          // 65536
#define NKT 16                    // K tiles of 64

// branch-free exact-GELU via A&S 7.1.26 erf approximation (|eps| < 1.5e-7)
__device__ __forceinline__ float gelu_bf(float x) {
    float z  = 0.70710678118f * x;
    float az = fabsf(z);
    float t  = __builtin_amdgcn_rcpf(fmaf(0.3275911f, az, 1.0f));
    float poly = fmaf(fmaf(fmaf(fmaf(1.061405429f, t, -1.453152027f), t,
                         1.421413741f), t, -0.284496736f), t, 0.254829592f) * t;
    float ex = __expf(-az * az);
    float er = copysignf(fmaf(-poly, ex, 1.0f), z);
    return 0.5f * x * (1.0f + er);
}

// ---------------- init logits with b2 (FALLBACK path only) ----------------------
__global__ void sr_init_logits(float* __restrict__ logits, const float* __restrict__ b2) {
    int i = blockIdx.x * 256 + threadIdx.x;
    if (i < MROWS * 2) logits[i] = b2[i & 1];
}

// ---------------- W1 first half -> bf16 -----------------------------------------
__global__ void sr_conv_w1(const float* __restrict__ W1, __bf16* __restrict__ Bt) {
    int gid = blockIdx.x * 256 + threadIdx.x;
    int h = gid >> 8;
    int kb = (gid & 255) * 4;
    float4 v = *(const float4*)&W1[(size_t)h * 2048 + kb];
    BF4 o;
    o.h[0] = (__bf16)v.x; o.h[1] = (__bf16)v.y; o.h[2] = (__bf16)v.z; o.h[3] = (__bf16)v.w;
    *(BF4*)&Bt[(size_t)h * 1024 + kb] = o;
}

// ---------------- enc f32 -> bf16 (Ab) ------------------------------------------
__global__ void sr_conv_enc(const float* __restrict__ enc, __bf16* __restrict__ Ab) {
    size_t i = ((size_t)blockIdx.x * 256 + threadIdx.x) * 8;
    float4 v0 = *(const float4*)&enc[i];
    float4 v1 = *(const float4*)&enc[i + 4];
    BF8 t;
    t.h[0] = (__bf16)v0.x; t.h[1] = (__bf16)v0.y;
    t.h[2] = (__bf16)v0.z; t.h[3] = (__bf16)v0.w;
    t.h[4] = (__bf16)v1.x; t.h[5] = (__bf16)v1.y;
    t.h[6] = (__bf16)v1.z; t.h[7] = (__bf16)v1.w;
    *(BF8*)&Ab[i] = t;
}

// ---------------- formula embedding: index-gather (labels scanned, not enc) -----
__global__ void sr_femb(const float* __restrict__ enc, const int* __restrict__ lab,
                        float* __restrict__ femb) {
    __shared__ int cnt;
    __shared__ int idl[64];                 // plenty: exactly 1 hit/sample by construction
    int b = blockIdx.x;
    int tid = threadIdx.x;
    if (tid == 0) cnt = 0;
    __syncthreads();
    for (int s = tid; s < SEQ; s += 256)
        if (lab[b * SEQ + s] == 2) {
            int p = atomicAdd(&cnt, 1);
            if (p < 64) idl[p] = s;
        }
    __syncthreads();
    float4 a = {0.f, 0.f, 0.f, 0.f};
    int n = cnt < 64 ? cnt : 64;
    for (int i = 0; i < n; ++i) {
        float4 v = *(const float4*)&enc[((size_t)b * SEQ + idl[i]) * HID + tid * 4];
        a.x += v.x; a.y += v.y; a.z += v.z; a.w += v.w;
    }
    *(float4*)&femb[b * HID + tid * 4] = a;
}

// ---------------- fc[b,h] = b1[h] + femb[b,:] . W1[h,1024:2048] -----------------
__global__ void sr_fc(const float* __restrict__ femb, const float* __restrict__ W1,
                      const float* __restrict__ b1, float* __restrict__ fcout) {
    int gw = (blockIdx.x * 256 + threadIdx.x) >> 6;
    int lane = threadIdx.x & 63;
    for (int i = 0; i < 16; ++i) {
        int d = gw * 16 + i;
        int b = d >> 10, h = d & 1023;
        const float* fe = femb + b * HID;
        const float* wr = W1 + (size_t)h * 2048 + 1024;
        float p = 0.f;
        #pragma unroll
        for (int t = 0; t < 16; ++t) {
            int k = lane + t * 64;
            p += fe[k] * wr[k];
        }
        #pragma unroll
        for (int off = 32; off; off >>= 1) p += __shfl_down(p, off);
        if (lane == 0) fcout[d] = p + b1[h];
    }
}

// ---------------- PRIMARY: 256^2 2-phase GEMM, 16 waves (4x4), 64x64/wave -------
__global__ __launch_bounds__(1024, 4)
void sr_gemm14(const __bf16* __restrict__ Ab, const __bf16* __restrict__ Bt,
               const float* __restrict__ fc, const float* __restrict__ W2,
               float* __restrict__ partg) {
    // 139264 B: loop uses first 131072 as LA[2]|LB[2]; epilogue reuses all as red[]
    __shared__ __align__(16) unsigned char smem[139264];
    __bf16* LAb = (__bf16*)smem;                    // LA[buf] = LAb + buf*16384
    __bf16* LBb = (__bf16*)(smem + 65536);          // LB[buf] = LBb + buf*16384
    float*  red = (float*)smem;                     // [256*2][68] f32 epilogue scratch

    int bid = blockIdx.x;
    int lgc = (bid & 7) * 128 + (bid >> 3);         // XCD-bijective (1024 % 8 == 0)
    int pm = lgc >> 2, pn = lgc & 3;
    const int row0 = pm * 256, col0 = pn * 256;

    int tid = threadIdx.x;
    int wid = tid >> 6, lane = tid & 63;
    int wr = wid >> 2, wc = wid & 3;                // 4x4 wave grid
    int l15 = lane & 15, lq = lane >> 4;

    f32x4 acc[4][4] = {};                           // [m][n], 64 f32/lane

    #define STAGE(buf, kt) do {                                                   \
        _Pragma("unroll")                                                         \
        for (int i = 0; i < 2; ++i) {                                             \
            int q = i * 1024 + tid;                                               \
            int r = q >> 3, c = q & 7;                                            \
            int sc = (c ^ (r & 7)) * 8 + (kt) * 64;                               \
            __builtin_amdgcn_global_load_lds(                                     \
                (glb_void*)(Ab + (size_t)(row0 + r) * HID + sc),                  \
                (lds_void*)(LAb + (buf) * 16384 + q * 8), 16, 0, 0);              \
            __builtin_amdgcn_global_load_lds(                                     \
                (glb_void*)(Bt + (size_t)(col0 + r) * HID + sc),                  \
                (lds_void*)(LBb + (buf) * 16384 + q * 8), 16, 0, 0);              \
        }                                                                         \
    } while (0)

    STAGE(0, 0);
    __syncthreads();

    int cur = 0;
    for (int kt = 0; kt < NKT; ++kt) {
        if (kt + 1 < NKT) STAGE(cur ^ 1, kt + 1);

        const __bf16* LAc = LAb + cur * 16384;
        const __bf16* LBc = LBb + cur * 16384;
        bf16x8 bfr[4][2];
        #pragma unroll
        for (int n = 0; n < 4; ++n)
            #pragma unroll
            for (int kk = 0; kk < 2; ++kk) {
                int r = wc * 64 + n * 16 + l15;
                bfr[n][kk] = *(const bf16x8*)
                    &LBc[r * 64 + (((kk * 4 + lq) ^ (r & 7)) * 8)];
            }
        #pragma unroll
        for (int m = 0; m < 4; ++m) {
            bf16x8 af[2];
            #pragma unroll
            for (int kk = 0; kk < 2; ++kk) {
                int r = wr * 64 + m * 16 + l15;
                af[kk] = *(const bf16x8*)
                    &LAc[r * 64 + (((kk * 4 + lq) ^ (r & 7)) * 8)];
            }
            #pragma unroll
            for (int n = 0; n < 4; ++n)
                #pragma unroll
                for (int kk = 0; kk < 2; ++kk)
                    acc[m][n] = __builtin_amdgcn_mfma_f32_16x16x32_bf16(
                        af[kk], bfr[n][kk], acc[m][n], 0, 0, 0);
        }
        __syncthreads();    // also fences the last reads of LA/LB before red reuse
        cur ^= 1;
    }
    #undef STAGE

    // ---- epilogue: per-lane gelu+W2 partials -> LDS transpose -> tree-free sum --
    int b = row0 >> 11;
    float fcv[4], w2a[4], w2b[4];
    #pragma unroll
    for (int n = 0; n < 4; ++n) {
        int h = col0 + wc * 64 + n * 16 + l15;
        fcv[n] = fc[b * HID + h];
        w2a[n] = W2[h];
        w2b[n] = W2[HID + h];
    }
    int e = wc * 16 + l15;                  // 0..63: which h-subgroup this lane covers
    #pragma unroll
    for (int m = 0; m < 4; ++m)
        #pragma unroll
        for (int j = 0; j < 4; ++j) {
            int rloc = wr * 64 + m * 16 + lq * 4 + j;
            float p0 = 0.f, p1 = 0.f;
            #pragma unroll
            for (int n = 0; n < 4; ++n) {
                float g = gelu_bf(acc[m][n][j] + fcv[n]);
                p0 += g * w2a[n];
                p1 += g * w2b[n];
            }
            red[(rloc * 2 + 0) * 68 + e] = p0;
            red[(rloc * 2 + 1) * 68 + e] = p1;
        }
    __syncthreads();
    {   // two threads per (row, class): each sums 32 partials (8 b128), shfl-combine
        int rc = tid >> 1, half = tid & 1;
        const f32x4* rp = (const f32x4*)&red[rc * 68 + half * 32];
        f32x4 sv = {0.f, 0.f, 0.f, 0.f};
        #pragma unroll
        for (int i = 0; i < 8; ++i) sv += rp[i];
        float s = sv[0] + sv[1] + sv[2] + sv[3];
        s += __shfl_xor(s, 1);
        if (half == 0) {
            int row = rc >> 1, c = rc & 1;
            partg[((size_t)pn * MROWS + row0 + row) * 2 + c] = s;
        }
    }
}

// ---------------- FALLBACK GEMM (atomics path, used only if ws too small) -------
__global__ __launch_bounds__(256, 2)
void sr_gemm_fused(const float* __restrict__ enc, const __bf16* __restrict__ Bt,
                   const float* __restrict__ fc, const float* __restrict__ W2,
                   float* __restrict__ logits) {
    __shared__ __bf16 As[128 * 64];
    __shared__ __bf16 Bs[128 * 64];

    int bid = blockIdx.x;
    int logical = (bid & 7) * 512 + (bid >> 3);
    int pm = logical >> 3;
    int pn = logical & 7;

    int tid = threadIdx.x;
    int wid = tid >> 6, lane = tid & 63;
    int wm = wid >> 1, wn = wid & 1;

    const int row0 = pm * 128;
    const int col0 = pn * 128;

    f32x4 acc[4][4] = {};

    for (int kt = 0; kt < 16; ++kt) {
        int k0 = kt * 64;
        #pragma unroll
        for (int i = 0; i < 4; ++i) {
            int q = i * 256 + tid;
            int r = q >> 3;
            int cb = (q & 7) * 8;
            const __bf16* src = Bt + (size_t)(col0 + r) * 1024 + k0 + cb;
            __builtin_amdgcn_global_load_lds((glb_void*)src, (lds_void*)&Bs[q * 8], 16, 0, 0);
        }
        #pragma unroll
        for (int pp = 0; pp < 4; ++pp) {
            int e = pp * 2048 + tid * 8;
            int r = e >> 6, c = e & 63;
            const float* src = enc + (size_t)(row0 + r) * 1024 + k0 + c;
            float4 f0 = *(const float4*)src;
            float4 f1 = *(const float4*)(src + 4);
            BF8 t;
            t.h[0] = (__bf16)f0.x; t.h[1] = (__bf16)f0.y;
            t.h[2] = (__bf16)f0.z; t.h[3] = (__bf16)f0.w;
            t.h[4] = (__bf16)f1.x; t.h[5] = (__bf16)f1.y;
            t.h[6] = (__bf16)f1.z; t.h[7] = (__bf16)f1.w;
            *(BF8*)&As[r * 64 + c] = t;
        }
        __syncthreads();
        int lrow = lane & 15;
        int ak = (lane >> 4) * 8;
        #pragma unroll
        for (int kk = 0; kk < 2; ++kk) {
            bf16x8 a[4], b[4];
            #pragma unroll
            for (int m = 0; m < 4; ++m)
                a[m] = *(const bf16x8*)&As[(wm * 64 + m * 16 + lrow) * 64 + kk * 32 + ak];
            #pragma unroll
            for (int n = 0; n < 4; ++n)
                b[n] = *(const bf16x8*)&Bs[(wn * 64 + n * 16 + lrow) * 64 + kk * 32 + ak];
            #pragma unroll
            for (int m = 0; m < 4; ++m)
                #pragma unroll
                for (int n = 0; n < 4; ++n)
                    acc[m][n] = __builtin_amdgcn_mfma_f32_16x16x32_bf16(a[m], b[n], acc[m][n], 0, 0, 0);
        }
        __syncthreads();
    }

    int bidx = row0 >> 11;
    float fcv[4], w2a[4], w2b[4];
    #pragma unroll
    for (int n = 0; n < 4; ++n) {
        int h = col0 + wn * 64 + n * 16 + (lane & 15);
        fcv[n] = fc[bidx * HID + h];
        w2a[n] = W2[h];
        w2b[n] = W2[HID + h];
    }
    #pragma unroll
    for (int m = 0; m < 4; ++m) {
        int rbase = row0 + wm * 64 + m * 16 + (lane >> 4) * 4;
        #pragma unroll
        for (int j = 0; j < 4; ++j) {
            float p0 = 0.f, p1 = 0.f;
            #pragma unroll
            for (int n = 0; n < 4; ++n) {
                float g = gelu_bf(acc[m][n][j] + fcv[n]);
                p0 += g * w2a[n];
                p1 += g * w2b[n];
            }
            #pragma unroll
            for (int off = 1; off < 16; off <<= 1) {
                p0 += __shfl_xor(p0, off);
                p1 += __shfl_xor(p1, off);
            }
            if ((lane & 15) == 0) {
                int rg = rbase + j;
                atomicAdd(&logits[rg * 2 + 0], p0);
                atomicAdd(&logits[rg * 2 + 1], p1);
            }
        }
    }
}

// ---------------- loss from partials: logits = b2 + sum_pn partg; CE ------------
__global__ void sr_loss_pg(const int* __restrict__ lab, const float* __restrict__ partg,
                           const float* __restrict__ b2, float* __restrict__ logits,
                           float* __restrict__ mask_out, float* __restrict__ sl,
                           float* __restrict__ validv) {
    int b = blockIdx.x;
    int tid = threadIdx.x;
    float b20 = b2[0], b21 = b2[1];
    float lsum = 0.f; int lcnt = 0;
    for (int s = tid; s < SEQ; s += 256) {
        size_t row = (size_t)b * SEQ + s;
        float l0 = b20, l1 = b21;
        #pragma unroll
        for (int q = 0; q < 4; ++q) {
            l0 += partg[((size_t)q * MROWS + row) * 2 + 0];
            l1 += partg[((size_t)q * MROWS + row) * 2 + 1];
        }
        logits[row * 2 + 0] = l0;
        logits[row * 2 + 1] = l1;
        int l = lab[row];
        bool hdr = (l == 0) || (l == 1);
        mask_out[row] = hdr ? 1.0f : 0.0f;
        if (hdr) {
            float mx = fmaxf(l0, l1);
            float lse = mx + logf(expf(l0 - mx) + expf(l1 - mx));
            lsum += lse - (l == 0 ? l0 : l1);
            lcnt++;
        }
    }
    #pragma unroll
    for (int off = 32; off; off >>= 1) {
        lsum += __shfl_down(lsum, off);
        lcnt += __shfl_down(lcnt, off);
    }
    __shared__ float wsum[4];
    __shared__ int wcnt[4];
    int wid = tid >> 6, lane = tid & 63;
    if (lane == 0) { wsum[wid] = lsum; wcnt[wid] = lcnt; }
    __syncthreads();
    if (tid == 0) {
        float S = wsum[0] + wsum[1] + wsum[2] + wsum[3];
        int C = wcnt[0] + wcnt[1] + wcnt[2] + wcnt[3];
        sl[b] = (C > 0) ? S / (float)C : 0.0f;
        validv[b] = (C > 0) ? 1.0f : 0.0f;
    }
}

// ---------------- loss reading logits directly (FALLBACK path) ------------------
__global__ void sr_loss(const int* __restrict__ lab, const float* __restrict__ logits,
                        float* __restrict__ mask_out, float* __restrict__ sl,
                        float* __restrict__ validv) {
    int b = blockIdx.x;
    int tid = threadIdx.x;
    float lsum = 0.f; int lcnt = 0;
    for (int s = tid; s < SEQ; s += 256) {
        int l = lab[b * SEQ + s];
        bool hdr = (l == 0) || (l == 1);
        mask_out[b * SEQ + s] = hdr ? 1.0f : 0.0f;
        if (hdr) {
            float l0 = logits[(b * SEQ + s) * 2];
            float l1 = logits[(b * SEQ + s) * 2 + 1];
            float mx = fmaxf(l0, l1);
            float lse = mx + logf(expf(l0 - mx) + expf(l1 - mx));
            lsum += lse - (l == 0 ? l0 : l1);
            lcnt++;
        }
    }
    #pragma unroll
    for (int off = 32; off; off >>= 1) {
        lsum += __shfl_down(lsum, off);
        lcnt += __shfl_down(lcnt, off);
    }
    __shared__ float wsum[4];
    __shared__ int wcnt[4];
    int wid = tid >> 6, lane = tid & 63;
    if (lane == 0) { wsum[wid] = lsum; wcnt[wid] = lcnt; }
    __syncthreads();
    if (tid == 0) {
        float S = wsum[0] + wsum[1] + wsum[2] + wsum[3];
        int C = wcnt[0] + wcnt[1] + wcnt[2] + wcnt[3];
        sl[b] = (C > 0) ? S / (float)C : 0.0f;
        validv[b] = (C > 0) ? 1.0f : 0.0f;
    }
}

__global__ void sr_final(const float* __restrict__ sl, const float* __restrict__ validv,
                         float* __restrict__ out) {
    if (threadIdx.x == 0) {
        float s = 0.f, v = 0.f;
        for (int b = 0; b < NB; ++b) { s += sl[b]; v += validv[b]; }
        out[0] = s / (v + 1e-6f);
    }
}

extern "C" void kernel_launch(void* const* d_in, const int* in_sizes, int n_in,
                              void* d_out, int out_size, void* d_ws, size_t ws_size,
                              hipStream_t stream) {
    const float* enc = (const float*)d_in[0];
    const int*   lab = (const int*)d_in[1];
    const float* W1  = (const float*)d_in[2];
    const float* b1  = (const float*)d_in[3];
    const float* W2  = (const float*)d_in[4];
    const float* b2  = (const float*)d_in[5];

    float* out     = (float*)d_out;
    float* loss    = out;
    float* logits  = out + 1;
    float* maskout = out + 1 + MROWS * 2;

    float* ws     = (float*)d_ws;
    float* femb   = ws;                            // 32768 f32
    float* fc     = ws + 32768;                    // 32768 f32
    float* sl     = ws + 65536;                    // 32
    float* validv = ws + 65568;                    // 32
    float* partg  = ws + 65600;                    // 524288 f32 (2 MB)
    __bf16* Bt    = (__bf16*)(ws + 65600 + 2 * 524288);  // 2 MB
    __bf16* Ab    = Bt + (size_t)HID * HID;              // 134.2 MB

    const size_t need = (65600u + 2u * 524288u) * 4u + (size_t)HID * HID * 2u
                      + (size_t)MROWS * HID * 2u;

    sr_conv_w1<<<1024, 256, 0, stream>>>(W1, Bt);
    sr_femb<<<32, 256, 0, stream>>>(enc, lab, femb);
    sr_fc<<<512, 256, 0, stream>>>(femb, W1, b1, fc);

    if (ws_size >= need) {
        sr_conv_enc<<<32768, 256, 0, stream>>>(enc, Ab);
        sr_gemm14<<<1024, 1024, 0, stream>>>(Ab, Bt, fc, W2, partg);
        sr_loss_pg<<<32, 256, 0, stream>>>(lab, partg, b2, logits, maskout, sl, validv);
    } else {
        sr_init_logits<<<512, 256, 0, stream>>>(logits, b2);
        sr_gemm_fused<<<4096, 256, 0, stream>>>(enc, Bt, fc, W2, logits);
        sr_loss<<<32, 256, 0, stream>>>(lab, logits, maskout, sl, validv);
    }

    sr_final<<<1, 64, 0, stream>>>(sl, validv, loss);
}